// Round 1
// baseline (221.253 us; speedup 1.0000x reference)
//
#include <hip/hip_runtime.h>
#include <math.h>

#define BB 64
#define RR 6912
#define II 8
#define CC 10
#define OO 16
#define NCH 64          // route chunks
#define RC 108          // routes per chunk (NCH*RC == RR)
#define TR 4            // routes per LDS tile (== waves per block)
#define NT 27           // tiles per chunk (TR*NT == RC)

// LDS: tiles need TR*BB*12 + TR*II*OO = 3072+512 = 3584 floats;
// epilogue reduction needs 256*18 = 4608 floats. Union them.
#define LDSF 4608

// ---------------- pass kernel ----------------
// MODE 0: uniform probs -> plain sum of priors
// MODE 1: logits = dot(priors, out0)        (online softmax)
// MODE 2: logits = dot(priors, out0+out1)   (online softmax)
template <int MODE>
__global__ __launch_bounds__(256) void pass_kernel(
    const float* __restrict__ x, const float* __restrict__ w,
    const float* __restrict__ outv_in,
    float* __restrict__ pacc, float* __restrict__ pm, float* __restrict__ pz)
{
    __shared__ __align__(16) float lds_raw[LDSF];
    float* xs  = lds_raw;          // [TR][BB][12] (padded stride 12)
    float* wsm = lds_raw + TR * BB * 12;  // [TR][II*OO]

    const int c     = blockIdx.x / NCH;
    const int chunk = blockIdx.x % NCH;
    const int t     = threadIdx.x;
    const int b     = t & 63;
    const int j     = t >> 6;      // wave index == route slot in tile

    const int r0base = chunk * RC;

    float acc[OO];
#pragma unroll
    for (int o = 0; o < OO; ++o) acc[o] = 0.f;
    float m = -INFINITY, Z = 0.f;

    float ov[OO];
    if (MODE != 0) {
#pragma unroll
        for (int o = 0; o < OO; ++o) ov[o] = outv_in[(c * BB + b) * OO + o];
    }

    const int lb = t >> 2;  // loader b
    const int lk = t & 3;   // loader route-in-tile

    for (int tile = 0; tile < NT; ++tile) {
        const int r0 = r0base + tile * TR;
        __syncthreads();
        // stage x[b', r0+lk, 0:8] -> xs[lk][b'][0:8]
        {
            const float* xp = x + ((size_t)lb * RR + (r0 + lk)) * II;
            float4 xa = *(const float4*)xp;
            float4 xb = *(const float4*)(xp + 4);
            float* dst = xs + (lk * BB + lb) * 12;
            *(float4*)(dst) = xa;
            *(float4*)(dst + 4) = xb;
        }
        // stage W[c, r0:r0+4, :, :] (512 floats) -> wsm
        if (t < 128) {
            const float4* wp = (const float4*)(w + ((size_t)c * RR + r0) * II * OO);
            ((float4*)wsm)[t] = wp[t];
        }
        __syncthreads();

        // compute priors for route r0+j, batch b, all 16 o
        float xr[II];
#pragma unroll
        for (int i = 0; i < II; ++i) xr[i] = xs[(j * BB + b) * 12 + i];
        float p[OO];
#pragma unroll
        for (int o = 0; o < OO; ++o) p[o] = 0.f;
#pragma unroll
        for (int i = 0; i < II; ++i) {
            const float* wrow = wsm + j * (II * OO) + i * OO;
#pragma unroll
            for (int o = 0; o < OO; ++o) p[o] = fmaf(xr[i], wrow[o], p[o]);
        }

        if (MODE == 0) {
#pragma unroll
            for (int o = 0; o < OO; ++o) acc[o] += p[o];
        } else {
            float d = 0.f;
#pragma unroll
            for (int o = 0; o < OO; ++o) d = fmaf(p[o], ov[o], d);
            const float nm  = fmaxf(m, d);
            const float sc  = __expf(m - nm);   // 0 on first route (m=-inf)
            const float wgt = __expf(d - nm);
            Z = Z * sc + wgt;
#pragma unroll
            for (int o = 0; o < OO; ++o) acc[o] = fmaf(acc[o], sc, wgt * p[o]);
            m = nm;
        }
    }

    // merge the TR per-wave partials -> one partial per (c,chunk,b)
    __syncthreads();
    {
        float* myred = lds_raw + t * 18;
#pragma unroll
        for (int o = 0; o < OO; ++o) myred[o] = acc[o];
        myred[16] = m;
        myred[17] = Z;
    }
    __syncthreads();
    if (t < BB) {
        const int b0 = t;
        float A2[OO];
#pragma unroll
        for (int o = 0; o < OO; ++o) A2[o] = 0.f;
        float M2 = -INFINITY, Z2 = 0.f;
        if (MODE == 0) {
            for (int k = 0; k < TR; ++k) {
                const float* rp = lds_raw + (k * BB + b0) * 18;
#pragma unroll
                for (int o = 0; o < OO; ++o) A2[o] += rp[o];
            }
        } else {
            for (int k = 0; k < TR; ++k)
                M2 = fmaxf(M2, lds_raw[(k * BB + b0) * 18 + 16]);
            for (int k = 0; k < TR; ++k) {
                const float* rp = lds_raw + (k * BB + b0) * 18;
                const float e = __expf(rp[16] - M2);
                Z2 += rp[17] * e;
#pragma unroll
                for (int o = 0; o < OO; ++o) A2[o] = fmaf(rp[o], e, A2[o]);
            }
        }
        const int pidx = (c * NCH + chunk) * BB + b0;
        float* ap = pacc + (size_t)pidx * OO;
#pragma unroll
        for (int o = 0; o < OO; o += 4)
            *(float4*)(ap + o) = make_float4(A2[o], A2[o + 1], A2[o + 2], A2[o + 3]);
        if (MODE != 0) { pm[pidx] = M2; pz[pidx] = Z2; }
    }
}

// ---------------- combine kernel ----------------
// MODE 0: s = sum/R, write out0 = squash(s)
// MODE 1: merge softmax partials, write outsum = out0 + squash(s)
// MODE 2: merge softmax partials, write final = squash(s)
template <int MODE>
__global__ __launch_bounds__(256) void combine_kernel(
    const float* __restrict__ pacc, const float* __restrict__ pm,
    const float* __restrict__ pz, const float* __restrict__ out0,
    float* __restrict__ outw)
{
    const int idx = blockIdx.x * 256 + threadIdx.x;  // < CC*BB*OO = 10240
    const int o = idx & 15;
    const int b = (idx >> 4) & 63;
    const int c = idx >> 10;

    float s = 0.f;
    if (MODE == 0) {
#pragma unroll 8
        for (int p = 0; p < NCH; ++p)
            s += pacc[(size_t)((c * NCH + p) * BB + b) * OO + o];
        s *= (1.0f / RR);
    } else {
        float M = -INFINITY, Zt = 0.f;
#pragma unroll 4
        for (int p = 0; p < NCH; ++p) {
            const int pi = (c * NCH + p) * BB + b;
            const float mj = pm[pi];
            const float zj = pz[pi];
            const float aj = pacc[(size_t)pi * OO + o];
            const float nM = fmaxf(M, mj);
            const float sM = __expf(M - nM);
            const float sj = __expf(mj - nM);
            s  = s  * sM + aj * sj;
            Zt = Zt * sM + zj * sj;
            M = nM;
        }
        s /= Zt;
    }

    // squash across the 16 lanes sharing (c,b)
    float sq = s * s;
#pragma unroll
    for (int w = 1; w < 16; w <<= 1) sq += __shfl_xor(sq, w);
    const float val = s * sqrtf(sq) / (1.f + sq);

    if (MODE == 1)
        outw[idx] = val + out0[idx];
    else
        outw[idx] = val;
}

extern "C" void kernel_launch(void* const* d_in, const int* in_sizes, int n_in,
                              void* d_out, int out_size, void* d_ws, size_t ws_size,
                              hipStream_t stream)
{
    const float* x = (const float*)d_in[0];
    const float* w = (const float*)d_in[1];
    float* out = (float*)d_out;

    float* ws = (float*)d_ws;
    float* pacc   = ws;                                  // CC*NCH*BB*OO
    float* pm     = pacc + (size_t)CC * NCH * BB * OO;   // CC*NCH*BB
    float* pz     = pm + CC * NCH * BB;                  // CC*NCH*BB
    float* out0   = pz + CC * NCH * BB;                  // CC*BB*OO
    float* outsum = out0 + CC * BB * OO;                 // CC*BB*OO

    const dim3 gp(CC * NCH), bp(256);
    const dim3 gc(CC * BB * OO / 256), bc(256);

    pass_kernel<0><<<gp, bp, 0, stream>>>(x, w, nullptr, pacc, pm, pz);
    combine_kernel<0><<<gc, bc, 0, stream>>>(pacc, pm, pz, nullptr, out0);
    pass_kernel<1><<<gp, bp, 0, stream>>>(x, w, out0, pacc, pm, pz);
    combine_kernel<1><<<gc, bc, 0, stream>>>(pacc, pm, pz, out0, outsum);
    pass_kernel<2><<<gp, bp, 0, stream>>>(x, w, outsum, pacc, pm, pz);
    combine_kernel<2><<<gc, bc, 0, stream>>>(pacc, pm, pz, nullptr, out);
}